// Round 2
// baseline (622.315 us; speedup 1.0000x reference)
//
#include <hip/hip_runtime.h>
#include <math.h>

#define LL 4096
#define NB 64
#define WW 64
#define NMODES 32
#define NCIN 24
#define NLAY 4
#define NPROJ 128
#define NSTC 16
#define NSPLIT 16

static __device__ __forceinline__ float gelu_tanh(float x){
    const float c0 = 0.7978845608028654f;   // sqrt(2/pi)
    const float c1 = 0.044715f;
    float t = tanhf(c0*(x + c1*x*x*x));
    return 0.5f*x*(1.0f+t);
}

// ---------------- tables ----------------
// TD[n][x], n<32: cos(2pi n x / L); n>=32: -sin(2pi (n-32) x / L)   (forward rfft basis)
// TI[k][x], k<32: scaled cos for irfft; k>=32: scaled -sin. Row 32 (Im of bin0) = 0.
__global__ void k_tables(float* __restrict__ TD, float* __restrict__ TI){
    int idx = blockIdx.x*256 + threadIdx.x;
    if (idx >= LL*NMODES) return;
    int x = idx & (LL-1);
    int k = idx >> 12;
    int ph = (k*x) & (LL-1);                 // exact integer phase mod L
    float ang = (6.283185307179586f/(float)LL)*(float)ph;
    float c = cosf(ang), s = sinf(ang);
    TD[(size_t)k*LL + x] = c;
    TD[(size_t)(k+NMODES)*LL + x] = -s;
    if (k == 0){
        TI[x] = 1.0f/(float)LL;
        TI[(size_t)NMODES*LL + x] = 0.0f;    // irfft ignores Im of bin 0
    } else {
        TI[(size_t)k*LL + x] = (2.0f/(float)LL)*c;
        TI[(size_t)(k+NMODES)*LL + x] = -(2.0f/(float)LL)*s;
    }
}

// ---------------- spectral weight transpose: [l][i][o][m] -> [l][m][i][o] ----------------
__global__ void k_wt(const float* __restrict__ wr, const float* __restrict__ wi,
                     float* __restrict__ wrT, float* __restrict__ wiT){
    int idx = blockIdx.x*256 + threadIdx.x;
    if (idx >= NLAY*WW*WW*NMODES) return;
    int m = idx & 31;
    int o = (idx >> 5) & 63;
    int i = (idx >> 11) & 63;
    int l = idx >> 17;
    size_t dst = (((size_t)l*NMODES + m)*WW + i)*WW + o;
    wrT[dst] = wr[idx];
    wiT[dst] = wi[idx];
}

// ---------------- lifting: h[b][c][x] = sum_j cat(u,z)[b,x,j] * fc0_w[j][c] + fc0_b[c] ----------------
__global__ void k_lift(const float* __restrict__ u, const float* __restrict__ z,
                       const float* __restrict__ w0, const float* __restrict__ b0,
                       float* __restrict__ h){
    __shared__ float Ws[NCIN*WW];
    __shared__ float Bs[WW];
    __shared__ float Zs[16];
    int b = blockIdx.y;
    int x0 = blockIdx.x*256;
    int tid = threadIdx.x;
    for (int i = tid; i < NCIN*WW; i += 256) Ws[i] = w0[i];
    if (tid < WW) Bs[tid] = b0[tid];
    if (tid < 16) Zs[tid] = z[b*16 + tid];
    __syncthreads();
    int x = x0 + tid;
    const float4* up = (const float4*)(u + ((size_t)b*LL + x)*8);
    float4 a0 = up[0], a1 = up[1];
    float ur[8] = {a0.x,a0.y,a0.z,a0.w,a1.x,a1.y,a1.z,a1.w};
    float zr[16];
    #pragma unroll
    for (int j=0;j<16;j++) zr[j] = Zs[j];
    for (int c=0;c<WW;c++){
        float acc = Bs[c];
        #pragma unroll
        for (int j=0;j<8;j++)  acc += ur[j]*Ws[j*WW+c];
        #pragma unroll
        for (int j=0;j<16;j++) acc += zr[j]*Ws[(8+j)*WW+c];
        h[((size_t)b*WW + c)*LL + x] = acc;
    }
}

// ---------------- truncated DFT (split-K GEMM) ----------------
// part[s][row][n] = sum_{x in split s} h[row][x]*TD[n][x]
// grid (64 row-tiles, 16 splits), 256 threads. Tile: 64 rows x 64 n, split K=256, chunk 64.
// Occupancy: 35 KB LDS -> 4 blocks/CU -> 16 waves/CU (vs 1 block/CU in the 128-row version).
__global__ void k_dft(const float* __restrict__ h, const float* __restrict__ TD,
                      float* __restrict__ part){
    __shared__ float Ah[64*68];
    __shared__ float Tn[64*68];
    int rt = blockIdx.x;
    int s  = blockIdx.y;
    int tid = threadIdx.x;
    int rowBase = rt*64;
    int rg = tid >> 3;     // 0..31  -> rows rg, rg+32
    int j  = tid & 7;      // n cols j + 8*q
    float acc[2][8];
    #pragma unroll
    for (int i=0;i<2;i++)
        #pragma unroll
        for (int q=0;q<8;q++) acc[i][q] = 0.f;

    for (int kc=0; kc<256; kc+=64){
        int kb = s*256 + kc;
        __syncthreads();
        #pragma unroll
        for (int t=0;t<4;t++){
            int f = tid + t*256;
            int rr = f >> 4, xo = (f & 15)*4;
            *(float4*)&Ah[rr*68 + xo] = *(const float4*)(h + (size_t)(rowBase+rr)*LL + kb + xo);
        }
        #pragma unroll
        for (int t=0;t<4;t++){
            int f = tid + t*256;
            int nn = f >> 4, xo = (f & 15)*4;
            *(float4*)&Tn[nn*68 + xo] = *(const float4*)(TD + (size_t)nn*LL + kb + xo);
        }
        __syncthreads();
        for (int kk=0; kk<64; kk+=4){
            float a[2][4];
            #pragma unroll
            for (int i=0;i<2;i++){
                float4 t = *(const float4*)&Ah[(rg+32*i)*68 + kk];
                a[i][0]=t.x; a[i][1]=t.y; a[i][2]=t.z; a[i][3]=t.w;
            }
            float tn[8][4];
            #pragma unroll
            for (int q=0;q<8;q++){
                float4 t = *(const float4*)&Tn[(j+8*q)*68 + kk];
                tn[q][0]=t.x; tn[q][1]=t.y; tn[q][2]=t.z; tn[q][3]=t.w;
            }
            #pragma unroll
            for (int d=0;d<4;d++)
                #pragma unroll
                for (int i=0;i<2;i++)
                    #pragma unroll
                    for (int q=0;q<8;q++)
                        acc[i][q] += a[i][d]*tn[q][d];
        }
    }
    #pragma unroll
    for (int i=0;i<2;i++)
        #pragma unroll
        for (int q=0;q<8;q++)
            part[((size_t)s*4096 + rowBase + rg + 32*i)*64 + j + 8*q] = acc[i][q];
}

// ---------------- reduce partials -> hfT[b][m][{re,im}][i] ----------------
__global__ void k_reduce(const float* __restrict__ part, float* __restrict__ hfT){
    int e = blockIdx.x*256 + threadIdx.x;       // < 64*32*128
    int i    = e & 63;
    int reim = (e >> 6) & 1;
    int m    = (e >> 7) & 31;
    int b    = e >> 12;
    int n = m + 32*reim;
    size_t rowoff = ((size_t)b*WW + i)*64 + n;
    float s = 0.f;
    #pragma unroll
    for (int sp=0; sp<NSPLIT; sp++) s += part[(size_t)sp*262144 + rowoff];
    hfT[e] = s;
}

// ---------------- mode mix: of[b][o][m]=Re, of[b][o][32+m]=Im ----------------
// grid (32 m, 64 b), 64 threads (o)
__global__ void k_mix(const float* __restrict__ hfT, const float* __restrict__ wrT,
                      const float* __restrict__ wiT, float* __restrict__ of){
    int m = blockIdx.x, b = blockIdx.y;
    int o = threadIdx.x;
    __shared__ float hr[64], hi[64];
    const float* row = hfT + ((size_t)b*NMODES + m)*128;
    hr[o] = row[o];
    hi[o] = row[64+o];
    __syncthreads();
    float ar = 0.f, ai = 0.f;
    const float* wr = wrT + (size_t)m*4096;   // [i][o]
    const float* wi = wiT + (size_t)m*4096;
    for (int i=0;i<64;i++){
        float wrv = wr[i*64+o], wiv = wi[i*64+o];
        float r = hr[i], im = hi[i];
        ar += r*wrv - im*wiv;
        ai += r*wiv + im*wrv;
    }
    of[((size_t)b*WW+o)*64 + m]      = ar;
    of[((size_t)b*WW+o)*64 + 32 + m] = ai;
}

// ---------------- fused iDFT + skip + bias + gelu ----------------
// per b: out[o][x] = sum_{k<64} skw[k][o]*h[b][k][x] + sum_{j<64} of[b][o][j]*TI[j][x] + skb[o]
// grid (32 x-tiles, 64 b), 256 threads. Tile 64 o x 128 x, K=128.
__global__ void k_fused(const float* __restrict__ h, const float* __restrict__ of,
                        const float* __restrict__ skw, const float* __restrict__ skb,
                        const float* __restrict__ TI, float* __restrict__ hout,
                        int do_gelu){
    __shared__ float As[64*132];
    __shared__ float Bs[32*136];
    int b  = blockIdx.y;
    int x0 = blockIdx.x*128;
    int tid = threadIdx.x;
    // stage A[o][k]: k<64 skip weights (transposed), k>=64 of rows (contiguous)
    for (int f = tid; f < 64*64; f += 256){
        int kk = f >> 6, o = f & 63;
        As[o*132 + kk] = skw[f];                       // skw[kk*64+o]
    }
    for (int f = tid; f < 64*64; f += 256){
        int o = f >> 6, j = f & 63;
        As[o*132 + 64 + j] = of[((size_t)b*WW + o)*64 + j];
    }
    int og = tid >> 4, xg = tid & 15;
    int o0 = og*4, xt = xg*4;                          // x elems: xt..xt+3 and xt+64..xt+67
    float acc[4][8];
    #pragma unroll
    for (int i=0;i<4;i++)
        #pragma unroll
        for (int e=0;e<8;e++) acc[i][e] = 0.f;

    for (int kc = 0; kc < 128; kc += 32){
        __syncthreads();
        for (int f = tid; f < 32*32; f += 256){        // 32 rows * 32 float4
            int rr = f >> 5;
            int xo4 = f & 31;
            int g = kc + rr;
            const float* src = (g < 64) ? (h  + ((size_t)b*WW + g)*LL + x0 + xo4*4)
                                        : (TI + (size_t)(g-64)*LL   + x0 + xo4*4);
            *(float4*)&Bs[rr*136 + xo4*4] = *(const float4*)src;
        }
        __syncthreads();
        for (int kk = 0; kk < 32; kk += 4){
            float a[4][4];
            #pragma unroll
            for (int i=0;i<4;i++){
                float4 t = *(const float4*)&As[(o0+i)*132 + kc + kk];
                a[i][0]=t.x; a[i][1]=t.y; a[i][2]=t.z; a[i][3]=t.w;
            }
            #pragma unroll
            for (int d=0;d<4;d++){
                float4 b0 = *(const float4*)&Bs[(kk+d)*136 + xt];
                float4 b1 = *(const float4*)&Bs[(kk+d)*136 + xt + 64];
                float bb[8] = {b0.x,b0.y,b0.z,b0.w,b1.x,b1.y,b1.z,b1.w};
                #pragma unroll
                for (int i=0;i<4;i++)
                    #pragma unroll
                    for (int e=0;e<8;e++)
                        acc[i][e] += a[i][d]*bb[e];
            }
        }
    }
    #pragma unroll
    for (int i=0;i<4;i++){
        int o = o0+i;
        float bias = skb[o];
        #pragma unroll
        for (int e=0;e<8;e++){
            float v = acc[i][e] + bias;
            if (do_gelu) v = gelu_tanh(v);
            acc[i][e] = v;
        }
        size_t base = ((size_t)b*WW + o)*LL + x0 + xt;
        *(float4*)&hout[base]      = make_float4(acc[i][0],acc[i][1],acc[i][2],acc[i][3]);
        *(float4*)&hout[base + 64] = make_float4(acc[i][4],acc[i][5],acc[i][6],acc[i][7]);
    }
}

// ---------------- final: layer-3 tail at x=L-1 + projection ----------------
__global__ void k_final(const float* __restrict__ h3, const float* __restrict__ of,
                        const float* __restrict__ skw, const float* __restrict__ skb,
                        const float* __restrict__ TI,
                        const float* __restrict__ w1, const float* __restrict__ b1,
                        const float* __restrict__ w2, const float* __restrict__ b2,
                        float* __restrict__ out){
    int b = blockIdx.x;
    int tid = threadIdx.x;  // 128
    __shared__ float hch[64];
    __shared__ float til[64];
    __shared__ float hv[64];
    __shared__ float qv[128];
    if (tid < 64) hch[tid] = h3[((size_t)b*WW + tid)*LL + (LL-1)];
    else          til[tid-64] = TI[(size_t)(tid-64)*LL + (LL-1)];
    __syncthreads();
    if (tid < 64){
        int o = tid;
        float acc = skb[o];
        const float* ofr = of + ((size_t)b*WW + o)*64;
        #pragma unroll
        for (int j=0;j<64;j++) acc += ofr[j]*til[j];
        #pragma unroll
        for (int i=0;i<64;i++) acc += hch[i]*skw[i*64+o];
        hv[o] = acc;                       // last layer: no gelu
    }
    __syncthreads();
    {
        int p = tid;
        float acc = b1[p];
        for (int o=0;o<64;o++) acc += hv[o]*w1[o*NPROJ+p];
        qv[p] = gelu_tanh(acc);
    }
    __syncthreads();
    if (tid < NSTC){
        int s = tid;
        float acc = b2[s];
        for (int p=0;p<NPROJ;p++) acc += qv[p]*w2[p*NSTC+s];
        out[b*NSTC + s] = acc;
    }
}

extern "C" void kernel_launch(void* const* d_in, const int* in_sizes, int n_in,
                              void* d_out, int out_size, void* d_ws, size_t ws_size,
                              hipStream_t stream) {
    const float* u     = (const float*)d_in[0];
    const float* z     = (const float*)d_in[1];
    // d_in[2] = t, unused by reference
    const float* fc0w  = (const float*)d_in[3];
    const float* fc0b  = (const float*)d_in[4];
    const float* swr   = (const float*)d_in[5];
    const float* swi   = (const float*)d_in[6];
    const float* skw   = (const float*)d_in[7];
    const float* skb   = (const float*)d_in[8];
    const float* fc1w  = (const float*)d_in[9];
    const float* fc1b  = (const float*)d_in[10];
    const float* fc2w  = (const float*)d_in[11];
    const float* fc2b  = (const float*)d_in[12];
    float* out = (float*)d_out;

    const size_t SZ_H    = (size_t)NB*WW*LL*4;          // 64 MiB
    const size_t SZ_TD   = (size_t)64*LL*4;             // 1 MiB
    const size_t SZ_TI   = SZ_TD;
    const size_t SZ_PART = (size_t)NSPLIT*4096*64*4;    // 16 MiB
    const size_t SZ_HFT  = (size_t)64*32*128*4;         // 1 MiB
    const size_t SZ_OF   = (size_t)64*64*64*4;          // 1 MiB
    const size_t SZ_WT   = (size_t)NLAY*NMODES*WW*WW*4; // 2 MiB

    size_t need = 2*SZ_H + SZ_TD + SZ_TI + SZ_PART + SZ_HFT + SZ_OF + 2*SZ_WT;
    if (ws_size < need) return;

    char* p = (char*)d_ws;
    float* hA   = (float*)p; p += SZ_H;
    float* hB   = (float*)p; p += SZ_H;
    float* TD   = (float*)p; p += SZ_TD;
    float* TI   = (float*)p; p += SZ_TI;
    float* part = (float*)p; p += SZ_PART;
    float* hfT  = (float*)p; p += SZ_HFT;
    float* of   = (float*)p; p += SZ_OF;
    float* wrT  = (float*)p; p += SZ_WT;
    float* wiT  = (float*)p; p += SZ_WT;

    k_tables<<<(LL*NMODES+255)/256, 256, 0, stream>>>(TD, TI);
    k_wt<<<(NLAY*WW*WW*NMODES+255)/256, 256, 0, stream>>>(swr, swi, wrT, wiT);
    k_lift<<<dim3(LL/256, NB), 256, 0, stream>>>(u, z, fc0w, fc0b, hA);

    float* hcur = hA;
    float* hnxt = hB;
    for (int l = 0; l < NLAY; l++){
        k_dft<<<dim3(64, NSPLIT), 256, 0, stream>>>(hcur, TD, part);
        k_reduce<<<(64*32*128)/256, 256, 0, stream>>>(part, hfT);
        k_mix<<<dim3(NMODES, NB), 64, 0, stream>>>(hfT, wrT + (size_t)l*NMODES*WW*WW,
                                                   wiT + (size_t)l*NMODES*WW*WW, of);
        if (l < NLAY-1){
            k_fused<<<dim3(LL/128, NB), 256, 0, stream>>>(hcur, of,
                skw + (size_t)l*WW*WW, skb + (size_t)l*WW, TI, hnxt, 1);
            float* tmp = hcur; hcur = hnxt; hnxt = tmp;
        }
    }
    k_final<<<NB, 128, 0, stream>>>(hcur, of, skw + (size_t)3*WW*WW, skb + (size_t)3*WW,
                                    TI, fc1w, fc1b, fc2w, fc2b, out);
}